// Round 11
// baseline (229.600 us; speedup 1.0000x reference)
//
#include <hip/hip_runtime.h>

#define TT 512

typedef _Float16 half8 __attribute__((ext_vector_type(8)));
typedef __attribute__((ext_vector_type(4))) float floatx4;

// raw workgroup barrier (no vmcnt/lgkmcnt drain); LDS FIFO is in-order per CU,
// validated R6-R12 (reads issued pre-barrier stay bit-exact vs post-barrier
// overwrites across 512 steps).
#define BAR() do { __asm__ volatile("" ::: "memory"); \
                   __builtin_amdgcn_s_barrier();      \
                   __asm__ volatile("" ::: "memory"); } while (0)

// 5-op tanh (R10' win, -32%): tanh(z) = fma(-2, rcp(exp2(z*2log2e)+1), 1).
__device__ __forceinline__ float fast_tanh(float z) {
#if __has_builtin(__builtin_amdgcn_exp2f)
    const float e = __builtin_amdgcn_exp2f(z * 2.8853900817779268f);
#else
    const float e = exp2f(z * 2.8853900817779268f);
#endif
#if __has_builtin(__builtin_amdgcn_rcpf)
    const float r = __builtin_amdgcn_rcpf(e + 1.f);
#else
    const float r = __frcp_rn(e + 1.f);
#endif
    return __builtin_fmaf(-2.f, r, 1.f);
}
__device__ __forceinline__ float f4e(const float4& v, int r) {
    return (r == 0) ? v.x : (r == 1) ? v.y : (r == 2) ? v.z : v.w;
}
__device__ __forceinline__ unsigned pk16(float a, float b) {
    const unsigned ua = __builtin_bit_cast(unsigned short, (_Float16)a);
    const unsigned ub = __builtin_bit_cast(unsigned short, (_Float16)b);
    return ua | (ub << 16);
}

// R11 = R10' champion (148.5 us) + split L1 accumulator chains.
// stepL1's two c-dependent MFMAs were serial (aB <- wB0*c0 <- wB1*c1, ~70 cy
// stacked on the 120-cy post-barrier c-read -> longest chain in the convoy).
// Split into independent aB/aB2 (and aA/aA2 on the prefetched-register side),
// summed in the epilogue: c-MFMAs now run in parallel, ~35 cy off the
// block-wide max chain. f32 add-order change only; R5 empirically showed the
// absmax signature (4.882812e-4) is invariant under exactly this split.
// All else bit-identical to R10' (lag-2 pipeline, 128 x 8 waves, raw barrier
// per interval, late L1 h0-prefetch off the release burst, 5-op tanh).
__global__ void __launch_bounds__(512, 1)
rnn2_r11(const float* __restrict__ x,
         const float* __restrict__ W_ih0, const float* __restrict__ W_hh0,
         const float* __restrict__ b_ih0, const float* __restrict__ b_hh0,
         const float* __restrict__ W_ih1, const float* __restrict__ W_hh1,
         const float* __restrict__ b_ih1, const float* __restrict__ b_hh1,
         const float* __restrict__ W_fc, const float* __restrict__ b_fc,
         float* __restrict__ out)
{
    __shared__ short h0f[2][1024];  // [parity][chunk*512 + 128q + 8n + j], fp16
    __shared__ short h1f[2][1024];
    __shared__ float red[4][16];

    const int tid = threadIdx.x;
    const int lane = tid & 63;
    const int w = tid >> 6;          // 0..7
    const int wq = w & 3;            // M-slice within the layer group
    const bool isL0 = (w < 4);
    const int n = lane & 15;
    const int q = lane >> 4;
    const int b0 = blockIdx.x * 16;

    // h1(-1) = 0 at parity 1 (read as c by L1 at interval 2)
    ((int*)&h1f[1][0])[tid] = 0;

    const int mrow = 16 * wq + n;
    const int m4 = 16 * wq + 4 * q;
    const int rbase = 128 * q + 8 * n;
    const int wbase = (2 * wq + (q >> 1)) * 128 + 8 * n + 4 * (q & 1);

    // ---- weight fragments, single fp16 RTNE (as R10) ----
    half8 wA[2], wB[2];  // L0: A=W_hh0 ; L1: A=W_ih1, B=W_hh1
    auto mkfrag = [&](const float* p, half8& hi) {
#pragma unroll
        for (int j = 0; j < 8; ++j) hi[j] = (_Float16)p[j];
    };
    float4 wih0v = {0, 0, 0, 0}, bv0 = {0, 0, 0, 0}, bv1 = {0, 0, 0, 0}, wfcv = {0, 0, 0, 0};
    if (isL0) {
#pragma unroll
        for (int k = 0; k < 2; ++k) mkfrag(W_hh0 + mrow * 64 + 32 * k + 8 * q, wA[k]);
        wih0v = *(const float4*)(W_ih0 + m4);
        bv0 = *(const float4*)(b_ih0 + m4);
        { float4 t = *(const float4*)(b_hh0 + m4); bv0.x += t.x; bv0.y += t.y; bv0.z += t.z; bv0.w += t.w; }
    } else {
#pragma unroll
        for (int k = 0; k < 2; ++k) {
            mkfrag(W_ih1 + mrow * 64 + 32 * k + 8 * q, wA[k]);
            mkfrag(W_hh1 + mrow * 64 + 32 * k + 8 * q, wB[k]);
        }
        bv1 = *(const float4*)(b_ih1 + m4);
        { float4 t = *(const float4*)(b_hh1 + m4); bv1.x += t.x; bv1.y += t.y; bv1.z += t.z; bv1.w += t.w; }
        wfcv = *(const float4*)(W_fc + m4);
    }

    const float* xp = x + (long)(b0 + n) * TT;
    const floatx4 zero4 = {0.f, 0.f, 0.f, 0.f};

    auto epi_write = [&](const floatx4& A, const floatx4& B, short* pf) {
        float h[4];
#pragma unroll
        for (int r = 0; r < 4; ++r) h[r] = fast_tanh(A[r] + B[r]);
        uint2 u;
        u.x = pk16(h[0], h[1]);
        u.y = pk16(h[2], h[3]);
        *(uint2*)&pf[wbase] = u;
    };

    // L0 interval: read h0[rp] (exposed, issued first), compute h0, write h0[wp]
    auto stepL0 = [&](int rp, int wp, float xvv) {
        half8 b0v = *(const half8*)&h0f[rp][rbase];
        half8 b1v = *(const half8*)&h0f[rp][rbase + 512];
        floatx4 aA = {__builtin_fmaf(xvv, wih0v.x, bv0.x), __builtin_fmaf(xvv, wih0v.y, bv0.y),
                      __builtin_fmaf(xvv, wih0v.z, bv0.z), __builtin_fmaf(xvv, wih0v.w, bv0.w)};
        floatx4 aB = zero4;
        aA = __builtin_amdgcn_mfma_f32_16x16x32_f16(wA[0], b0v, aA, 0, 0, 0);
        aB = __builtin_amdgcn_mfma_f32_16x16x32_f16(wA[1], b1v, aB, 0, 0, 0);
        epi_write(aA, aB, &h0f[wp][0]);
    };

    // L1 interval: c-reads first; FOUR independent MFMA accumulators (aA/aA2
    // on prefetched regs issue immediately; aB/aB2 on c run in PARALLEL after
    // the read, ~35 cy off the old serial chain). Sum in epilogue.
    // Late h0 prefetch stays after epi_write (R8's port-burst win).
    auto stepL1 = [&](int rc, int rbn, int wp, half8* bp) {
        half8 c0 = *(const half8*)&h1f[rc][rbase];
        half8 c1 = *(const half8*)&h1f[rc][rbase + 512];
        floatx4 aA = {bv1.x, bv1.y, bv1.z, bv1.w};
        aA = __builtin_amdgcn_mfma_f32_16x16x32_f16(wA[0], bp[0], aA, 0, 0, 0);
        floatx4 aA2 = __builtin_amdgcn_mfma_f32_16x16x32_f16(wA[1], bp[1], zero4, 0, 0, 0);
        floatx4 aB  = __builtin_amdgcn_mfma_f32_16x16x32_f16(wB[0], c0, zero4, 0, 0, 0);
        floatx4 aB2 = __builtin_amdgcn_mfma_f32_16x16x32_f16(wB[1], c1, zero4, 0, 0, 0);
        floatx4 sA = {aA[0] + aA2[0], aA[1] + aA2[1], aA[2] + aA2[2], aA[3] + aA2[3]};
        floatx4 sB = {aB[0] + aB2[0], aB[1] + aB2[1], aB[2] + aB2[2], aB[3] + aB2[3]};
        epi_write(sA, sB, &h1f[wp][0]);
        // late prefetch: LDS port idle here; h0f[rbn] stable this interval;
        // completion before next-interval overwrite = validated FIFO property.
        bp[0] = *(const half8*)&h0f[rbn][rbase];
        bp[1] = *(const half8*)&h0f[rbn][rbase + 512];
    };

    // ---- interval 0: L0 writes h0(0) -> parity 0 ----
    float xv = 0.f, xnext = 0.f;
    if (isL0) {
        const float xv0 = xp[0];
        float h[4];
#pragma unroll
        for (int r = 0; r < 4; ++r)
            h[r] = fast_tanh(__builtin_fmaf(xv0, f4e(wih0v, r), f4e(bv0, r)));
        uint2 u; u.x = pk16(h[0], h[1]); u.y = pk16(h[2], h[3]);
        *(uint2*)&h0f[0][wbase] = u;
        xv = xp[1];
        xnext = xp[2];
    }
    BAR();

    // ---- interval 1: L0 h0(1); L1 prefetches h0(0) ----
    half8 bp[2];
    if (isL0) {
        stepL0(0, 1, xv);
        xv = xnext; xnext = xp[3];
    } else {
        bp[0] = *(const half8*)&h0f[0][rbase];
        bp[1] = *(const half8*)&h0f[0][rbase + 512];
    }
    BAR();

    // ---- main loop: intervals i = 2..511 (pairs) ----
    // interval i: L0 computes h0(i); L1 computes h1(i-2), prefetches h0(i-1)
    for (int i = 2; i < 511; i += 2) {
        // P = 0
        if (isL0) {
            stepL0(1, 0, xv);
            xv = xnext; xnext = xp[(i + 2) & (TT - 1)];
        } else {
            stepL1(1, 1, 0, bp);
        }
        BAR();
        // P = 1
        if (isL0) {
            stepL0(0, 1, xv);
            xv = xnext; xnext = xp[(i + 3) & (TT - 1)];
        } else {
            stepL1(0, 0, 1, bp);
        }
        BAR();
    }

    // ---- tail interval 512: L1 computes h1(510), prefetches h0(511) ----
    if (!isL0) stepL1(1, 1, 0, bp);
    BAR();

    // ---- tail interval 513: L1 computes h1(511) in regs + FC dot ----
    float p = 0.f;
    if (!isL0) {
        half8 c0 = *(const half8*)&h1f[0][rbase];        // h1(510), parity 0
        half8 c1 = *(const half8*)&h1f[0][rbase + 512];
        floatx4 aA = {bv1.x, bv1.y, bv1.z, bv1.w};
        aA = __builtin_amdgcn_mfma_f32_16x16x32_f16(wA[0], bp[0], aA, 0, 0, 0);  // h0(511)
        floatx4 aA2 = __builtin_amdgcn_mfma_f32_16x16x32_f16(wA[1], bp[1], zero4, 0, 0, 0);
        floatx4 aB  = __builtin_amdgcn_mfma_f32_16x16x32_f16(wB[0], c0, zero4, 0, 0, 0);
        floatx4 aB2 = __builtin_amdgcn_mfma_f32_16x16x32_f16(wB[1], c1, zero4, 0, 0, 0);
#pragma unroll
        for (int r = 0; r < 4; ++r) {
            const float h = fast_tanh((aA[r] + aA2[r]) + (aB[r] + aB2[r]));
            p = __builtin_fmaf(h, f4e(wfcv, r), p);
        }
        p += __shfl_xor(p, 16, 64);
        p += __shfl_xor(p, 32, 64);
        if (lane < 16) red[wq][lane] = p;
    }
    __syncthreads();
    if (w == 4 && lane < 16)
        out[b0 + lane] = red[0][lane] + red[1][lane] + red[2][lane] + red[3][lane] + b_fc[0];
}

extern "C" void kernel_launch(void* const* d_in, const int* in_sizes, int n_in,
                              void* d_out, int out_size, void* d_ws, size_t ws_size,
                              hipStream_t stream) {
    const float* x     = (const float*)d_in[0];
    const float* W_ih0 = (const float*)d_in[1];
    const float* W_hh0 = (const float*)d_in[2];
    const float* b_ih0 = (const float*)d_in[3];
    const float* b_hh0 = (const float*)d_in[4];
    const float* W_ih1 = (const float*)d_in[5];
    const float* W_hh1 = (const float*)d_in[6];
    const float* b_ih1 = (const float*)d_in[7];
    const float* b_hh1 = (const float*)d_in[8];
    const float* W_fc  = (const float*)d_in[9];
    const float* b_fc  = (const float*)d_in[10];
    float* out = (float*)d_out;

    rnn2_r11<<<128, 512, 0, stream>>>(x, W_ih0, W_hh0, b_ih0, b_hh0,
                                      W_ih1, W_hh1, b_ih1, b_hh1,
                                      W_fc, b_fc, out);
}

// Round 12
// 224.706 us; speedup vs baseline: 1.0218x; 1.0218x over previous
//
#include <hip/hip_runtime.h>

#define TT 512

typedef _Float16 half4 __attribute__((ext_vector_type(4)));
typedef __attribute__((ext_vector_type(4))) float floatx4;

// raw workgroup barrier (no vmcnt/lgkmcnt drain); LDS FIFO is in-order per CU,
// validated R6-R12 (reads issued pre-barrier stay bit-exact vs post-barrier
// overwrites across 512 steps).
#define BAR() do { __asm__ volatile("" ::: "memory"); \
                   __builtin_amdgcn_s_barrier();      \
                   __asm__ volatile("" ::: "memory"); } while (0)

// 5-op tanh (R10 win, -32% on the 8-wave structure):
// tanh(z) = fma(-2, rcp(exp2(z*2log2e)+1), 1).
__device__ __forceinline__ float fast_tanh(float z) {
#if __has_builtin(__builtin_amdgcn_exp2f)
    const float e = __builtin_amdgcn_exp2f(z * 2.8853900817779268f);
#else
    const float e = exp2f(z * 2.8853900817779268f);
#endif
#if __has_builtin(__builtin_amdgcn_rcpf)
    const float r = __builtin_amdgcn_rcpf(e + 1.f);
#else
    const float r = __frcp_rn(e + 1.f);
#endif
    return __builtin_fmaf(-2.f, r, 1.f);
}
__device__ __forceinline__ float f4e(const float4& v, int r) {
    return (r == 0) ? v.x : (r == 1) ? v.y : (r == 2) ? v.z : v.w;
}
__device__ __forceinline__ unsigned pk16(float a, float b) {
    const unsigned ua = __builtin_bit_cast(unsigned short, (_Float16)a);
    const unsigned ub = __builtin_bit_cast(unsigned short, (_Float16)b);
    return ua | (ub << 16);
}

// R12 = R3 merged structure (harness-verified, 238 us with old tanh) + 5-op
// tanh graft. 128 blocks x 4 waves, 16 batch cols/block; wave wq owns h-rows
// [16wq,16wq+16) of BOTH layers (L0 at t=i, L1 at t=i-2 - two independent dep
// chains interleaving in ONE issue stream; 1 wave/SIMD; 4-wave barrier).
// K=64 recurrence = 4 accumulating K=16 MFMAs (dependent-accumulate kept:
// R11 showed splitting + v_add merge is slower). Own fragment register-
// resident (D->B identity, verified R2); partner fragments cross LDS lag-1
// (uint2 layout, 0 bank conflicts measured R3). L1's h0 inputs = partner
// values L0 read one interval earlier (register window) - no extra reads.
// Rationale: R3-old = 1044+67 cy despite 2x tanh/wave (structure hides VALU);
// converting 8 tanh/wave (vs 4 on the 8-wave, which saved 349 cy) should
// save >= 349 -> T_int <= 762, central 500-600 cy.
__global__ void __launch_bounds__(256, 1)
rnn2_m5(const float* __restrict__ x,
        const float* __restrict__ W_ih0, const float* __restrict__ W_hh0,
        const float* __restrict__ b_ih0, const float* __restrict__ b_hh0,
        const float* __restrict__ W_ih1, const float* __restrict__ W_hh1,
        const float* __restrict__ b_ih1, const float* __restrict__ b_hh1,
        const float* __restrict__ W_fc, const float* __restrict__ b_fc,
        float* __restrict__ out)
{
    __shared__ uint2 h0buf[2][256];   // [parity][(4*wq+g)*16 + n]
    __shared__ uint2 h1buf[2][256];
    __shared__ float red[4][16];

    const int tid  = threadIdx.x;
    const int lane = tid & 63;
    const int wq   = tid >> 6;    // wave: h-row tile [16wq, 16wq+16)
    const int g    = lane >> 4;   // row-quad within tile
    const int n    = lane & 15;   // batch column
    const int b0   = blockIdx.x * 16;

    // zero-init both parities of both state buffers
    {
        uint2 z; z.x = 0u; z.y = 0u;
        ((uint2*)h0buf)[tid]       = z;
        ((uint2*)h0buf)[tid + 256] = z;
        ((uint2*)h1buf)[tid]       = z;
        ((uint2*)h1buf)[tid + 256] = z;
    }

    // ---- weights, fp16 RTNE, rotated so index s=0 is the OWN fragment ----
    half4 wh0r[4], wi1r[4], wh1r[4];
    auto mk4 = [&](const float* p, half4& h) {
#pragma unroll
        for (int j = 0; j < 4; ++j) h[j] = (_Float16)p[j];
    };
#pragma unroll
    for (int s = 0; s < 4; ++s) {
        const int kt = (wq + s) & 3;
        mk4(W_hh0 + (16 * wq + n) * 64 + 16 * kt + 4 * g, wh0r[s]);
        mk4(W_ih1 + (16 * wq + n) * 64 + 16 * kt + 4 * g, wi1r[s]);
        mk4(W_hh1 + (16 * wq + n) * 64 + 16 * kt + 4 * g, wh1r[s]);
    }
    const float4 wv = *(const float4*)(W_ih0 + 16 * wq + 4 * g);
    float4 bs0, bs1;
    {
        const float4 a = *(const float4*)(b_ih0 + 16 * wq + 4 * g);
        const float4 c = *(const float4*)(b_hh0 + 16 * wq + 4 * g);
        bs0 = make_float4(a.x + c.x, a.y + c.y, a.z + c.z, a.w + c.w);
        const float4 d = *(const float4*)(b_ih1 + 16 * wq + 4 * g);
        const float4 e = *(const float4*)(b_hh1 + 16 * wq + 4 * g);
        bs1 = make_float4(d.x + e.x, d.y + e.y, d.z + e.z, d.w + e.w);
    }
    const float4 wfc = *(const float4*)(W_fc + 16 * wq + 4 * g);

    // state fragments (own tiles, registers); h(-1)=0
    const uint2 z2 = {0u, 0u};
    half4 st0 = __builtin_bit_cast(half4, z2);   // own h0(latest)
    half4 st1 = __builtin_bit_cast(half4, z2);   // own h1(latest)
    half4 own0d = st0;                           // own h0(i-2) for L1 input
    half4 r0d1 = st0, r0d2 = st0, r0d3 = st0;    // partner h0(i-2) for L1 input

    const float* xp = x + (long)(b0 + n) * TT;
    float xv = xp[0], xn = xp[1];

    const int k1 = (wq + 1) & 3, k2 = (wq + 2) & 3, k3 = (wq + 3) & 3;
    const int ri1 = (4 * k1 + g) * 16 + n;
    const int ri2 = (4 * k2 + g) * 16 + n;
    const int ri3 = (4 * k3 + g) * 16 + n;
    const int wi  = (4 * wq + g) * 16 + n;

    __syncthreads();   // one full barrier after zero-init

    auto body = [&](int i, bool doL0, bool doL1, bool last) {
        const int P = i & 1, R = P ^ 1;
        // lag-1 partner reads (exposed; hidden under register-operand MFMAs)
        uint2 q0a, q0b, q0c, q1a, q1b, q1c;
        if (!last) {
            q0a = h0buf[R][ri1];
            q0b = h0buf[R][ri2];
            q0c = h0buf[R][ri3];
        }
        if (doL1) {
            q1a = h1buf[R][ri1];
            q1b = h1buf[R][ri2];
            q1c = h1buf[R][ri3];
        }
        // L1: 5 register-operand MFMAs issue with no LDS dependency
        floatx4 a1;
        if (doL1) {
            a1[0] = bs1.x; a1[1] = bs1.y; a1[2] = bs1.z; a1[3] = bs1.w;
            a1 = __builtin_amdgcn_mfma_f32_16x16x16f16(wi1r[0], own0d, a1, 0, 0, 0);
            a1 = __builtin_amdgcn_mfma_f32_16x16x16f16(wi1r[1], r0d1, a1, 0, 0, 0);
            a1 = __builtin_amdgcn_mfma_f32_16x16x16f16(wi1r[2], r0d2, a1, 0, 0, 0);
            a1 = __builtin_amdgcn_mfma_f32_16x16x16f16(wi1r[3], r0d3, a1, 0, 0, 0);
            a1 = __builtin_amdgcn_mfma_f32_16x16x16f16(wh1r[0], st1, a1, 0, 0, 0);
        }
        floatx4 a0;
        if (doL0) {
            a0[0] = __builtin_fmaf(xv, wv.x, bs0.x);
            a0[1] = __builtin_fmaf(xv, wv.y, bs0.y);
            a0[2] = __builtin_fmaf(xv, wv.z, bs0.z);
            a0[3] = __builtin_fmaf(xv, wv.w, bs0.w);
            a0 = __builtin_amdgcn_mfma_f32_16x16x16f16(wh0r[0], st0, a0, 0, 0, 0);  // own, no wait
            a0 = __builtin_amdgcn_mfma_f32_16x16x16f16(wh0r[1], __builtin_bit_cast(half4, q0a), a0, 0, 0, 0);
            a0 = __builtin_amdgcn_mfma_f32_16x16x16f16(wh0r[2], __builtin_bit_cast(half4, q0b), a0, 0, 0, 0);
            a0 = __builtin_amdgcn_mfma_f32_16x16x16f16(wh0r[3], __builtin_bit_cast(half4, q0c), a0, 0, 0, 0);
            xv = xn; xn = xp[(i + 2) & (TT - 1)];
        }
        if (doL1) {
            a1 = __builtin_amdgcn_mfma_f32_16x16x16f16(wh1r[1], __builtin_bit_cast(half4, q1a), a1, 0, 0, 0);
            a1 = __builtin_amdgcn_mfma_f32_16x16x16f16(wh1r[2], __builtin_bit_cast(half4, q1b), a1, 0, 0, 0);
            a1 = __builtin_amdgcn_mfma_f32_16x16x16f16(wh1r[3], __builtin_bit_cast(half4, q1c), a1, 0, 0, 0);
        }
        // shift the lag-2 h0 window: this interval's h0(i-1) becomes next bp
        if (!last) {
            own0d = st0;
            r0d1 = __builtin_bit_cast(half4, q0a);
            r0d2 = __builtin_bit_cast(half4, q0b);
            r0d3 = __builtin_bit_cast(half4, q0c);
        }
        if (doL0) {
            uint2 u;
            u.x = pk16(fast_tanh(a0[0]), fast_tanh(a0[1]));
            u.y = pk16(fast_tanh(a0[2]), fast_tanh(a0[3]));
            h0buf[P][wi] = u;
            st0 = __builtin_bit_cast(half4, u);    // own frag, register-resident
        }
        if (doL1) {
            if (!last) {
                uint2 u;
                u.x = pk16(fast_tanh(a1[0]), fast_tanh(a1[1]));
                u.y = pk16(fast_tanh(a1[2]), fast_tanh(a1[3]));
                h1buf[P][wi] = u;
                st1 = __builtin_bit_cast(half4, u);
            } else {
                // h1(511) + FC partial for own 16 rows
                float p = 0.f;
#pragma unroll
                for (int r = 0; r < 4; ++r)
                    p = __builtin_fmaf(fast_tanh(a1[r]), f4e(wfc, r), p);
                p += __shfl_xor(p, 16, 64);
                p += __shfl_xor(p, 32, 64);
                if (lane < 16) red[wq][n] = p;
            }
        }
    };

    // pipeline fill: L1 inactive until its inputs exist
    body(0, true, false, false); BAR();
    body(1, true, false, false); BAR();
    // steady state: L0 at t=i, L1 at t=i-2
    for (int i = 2; i < 512; i += 2) {
        body(i,     true, true, false); BAR();
        body(i + 1, true, true, false); BAR();
    }
    // drain: L1 computes h1(510), then h1(511)+FC
    body(512, false, true, false); BAR();
    body(513, false, true, true);
    __syncthreads();
    if (wq == 0 && lane < 16)
        out[b0 + n] = red[0][n] + red[1][n] + red[2][n] + red[3][n] + b_fc[0];
}

extern "C" void kernel_launch(void* const* d_in, const int* in_sizes, int n_in,
                              void* d_out, int out_size, void* d_ws, size_t ws_size,
                              hipStream_t stream) {
    const float* x     = (const float*)d_in[0];
    const float* W_ih0 = (const float*)d_in[1];
    const float* W_hh0 = (const float*)d_in[2];
    const float* b_ih0 = (const float*)d_in[3];
    const float* b_hh0 = (const float*)d_in[4];
    const float* W_ih1 = (const float*)d_in[5];
    const float* W_hh1 = (const float*)d_in[6];
    const float* b_ih1 = (const float*)d_in[7];
    const float* b_hh1 = (const float*)d_in[8];
    const float* W_fc  = (const float*)d_in[9];
    const float* b_fc  = (const float*)d_in[10];
    float* out = (float*)d_out;

    rnn2_m5<<<128, 256, 0, stream>>>(x, W_ih0, W_hh0, b_ih0, b_hh0,
                                     W_ih1, W_hh1, b_ih1, b_hh1,
                                     W_fc, b_fc, out);
}

// Round 14
// 202.752 us; speedup vs baseline: 1.1324x; 1.1083x over previous
//
#include <hip/hip_runtime.h>

#define TT 512

typedef _Float16 half8 __attribute__((ext_vector_type(8)));
typedef __attribute__((ext_vector_type(4))) float floatx4;

// raw workgroup barrier (no vmcnt/lgkmcnt drain); LDS FIFO is in-order per CU,
// validated R6-R12 (reads issued pre-barrier stay bit-exact vs post-barrier
// overwrites across 512 steps).
#define BAR() do { __asm__ volatile("" ::: "memory"); \
                   __builtin_amdgcn_s_barrier();      \
                   __asm__ volatile("" ::: "memory"); } while (0)

// 5-op tanh (R10 win, -32%): tanh(z) = fma(-2, rcp(exp2(z*2log2e)+1), 1).
__device__ __forceinline__ float fast_tanh(float z) {
#if __has_builtin(__builtin_amdgcn_exp2f)
    const float e = __builtin_amdgcn_exp2f(z * 2.8853900817779268f);
#else
    const float e = exp2f(z * 2.8853900817779268f);
#endif
#if __has_builtin(__builtin_amdgcn_rcpf)
    const float r = __builtin_amdgcn_rcpf(e + 1.f);
#else
    const float r = __frcp_rn(e + 1.f);
#endif
    return __builtin_fmaf(-2.f, r, 1.f);
}
__device__ __forceinline__ float f4e(const float4& v, int r) {
    return (r == 0) ? v.x : (r == 1) ? v.y : (r == 2) ? v.z : v.w;
}
__device__ __forceinline__ unsigned pk16(float a, float b) {
    const unsigned ua = __builtin_bit_cast(unsigned short, (_Float16)a);
    const unsigned ub = __builtin_bit_cast(unsigned short, (_Float16)b);
    return ua | (ub << 16);
}

// R14 = R13 resubmitted (infra failure last round; kernel never ran).
// R13 = R10' champion (148.5 us) + full MFMA-chain accumulation.
// R11 lesson inverted into a win: dependent MFMA C-in accumulation is cheaper
// than parallel MFMAs + v_add merge (the adds sit on the tanh-input critical
// path). The champion still had 4 v_adds/step (aA+aB); this chains ALL MFMAs
// into ONE accumulator and deletes the adds. stepL1 chains bp[0],bp[1]
// (register-ready - issue immediately, hiding the c-read latency) then c0,c1.
// f32 summation-order change only (absmax signature invariant under reorder,
// evidenced R3/R5/R11/R12). All else identical to R10' (lag-2 pipeline,
// 128 x 8 waves, raw barrier/interval, late h0-prefetch, 5-op tanh).
__global__ void __launch_bounds__(512, 1)
rnn2_chain(const float* __restrict__ x,
           const float* __restrict__ W_ih0, const float* __restrict__ W_hh0,
           const float* __restrict__ b_ih0, const float* __restrict__ b_hh0,
           const float* __restrict__ W_ih1, const float* __restrict__ W_hh1,
           const float* __restrict__ b_ih1, const float* __restrict__ b_hh1,
           const float* __restrict__ W_fc, const float* __restrict__ b_fc,
           float* __restrict__ out)
{
    __shared__ short h0f[2][1024];  // [parity][chunk*512 + 128q + 8n + j], fp16
    __shared__ short h1f[2][1024];
    __shared__ float red[4][16];

    const int tid = threadIdx.x;
    const int lane = tid & 63;
    const int w = tid >> 6;          // 0..7
    const int wq = w & 3;            // M-slice within the layer group
    const bool isL0 = (w < 4);
    const int n = lane & 15;
    const int q = lane >> 4;
    const int b0 = blockIdx.x * 16;

    // h1(-1) = 0 at parity 1 (read as c by L1 at interval 2)
    ((int*)&h1f[1][0])[tid] = 0;

    const int mrow = 16 * wq + n;
    const int m4 = 16 * wq + 4 * q;
    const int rbase = 128 * q + 8 * n;
    const int wbase = (2 * wq + (q >> 1)) * 128 + 8 * n + 4 * (q & 1);

    // ---- weight fragments, single fp16 RTNE (as R10) ----
    half8 wA[2], wB[2];  // L0: A=W_hh0 ; L1: A=W_ih1, B=W_hh1
    auto mkfrag = [&](const float* p, half8& hi) {
#pragma unroll
        for (int j = 0; j < 8; ++j) hi[j] = (_Float16)p[j];
    };
    float4 wih0v = {0, 0, 0, 0}, bv0 = {0, 0, 0, 0}, bv1 = {0, 0, 0, 0}, wfcv = {0, 0, 0, 0};
    if (isL0) {
#pragma unroll
        for (int k = 0; k < 2; ++k) mkfrag(W_hh0 + mrow * 64 + 32 * k + 8 * q, wA[k]);
        wih0v = *(const float4*)(W_ih0 + m4);
        bv0 = *(const float4*)(b_ih0 + m4);
        { float4 t = *(const float4*)(b_hh0 + m4); bv0.x += t.x; bv0.y += t.y; bv0.z += t.z; bv0.w += t.w; }
    } else {
#pragma unroll
        for (int k = 0; k < 2; ++k) {
            mkfrag(W_ih1 + mrow * 64 + 32 * k + 8 * q, wA[k]);
            mkfrag(W_hh1 + mrow * 64 + 32 * k + 8 * q, wB[k]);
        }
        bv1 = *(const float4*)(b_ih1 + m4);
        { float4 t = *(const float4*)(b_hh1 + m4); bv1.x += t.x; bv1.y += t.y; bv1.z += t.z; bv1.w += t.w; }
        wfcv = *(const float4*)(W_fc + m4);
    }

    const float* xp = x + (long)(b0 + n) * TT;

    auto epi_write = [&](const floatx4& A, short* pf) {
        float h[4];
#pragma unroll
        for (int r = 0; r < 4; ++r) h[r] = fast_tanh(A[r]);
        uint2 u;
        u.x = pk16(h[0], h[1]);
        u.y = pk16(h[2], h[3]);
        *(uint2*)&pf[wbase] = u;
    };

    // L0 interval: read h0[rp] (exposed, issued first), single chained
    // accumulator (no epilogue adds), write h0[wp]
    auto stepL0 = [&](int rp, int wp, float xvv) {
        half8 b0v = *(const half8*)&h0f[rp][rbase];
        half8 b1v = *(const half8*)&h0f[rp][rbase + 512];
        floatx4 aA = {__builtin_fmaf(xvv, wih0v.x, bv0.x), __builtin_fmaf(xvv, wih0v.y, bv0.y),
                      __builtin_fmaf(xvv, wih0v.z, bv0.z), __builtin_fmaf(xvv, wih0v.w, bv0.w)};
        aA = __builtin_amdgcn_mfma_f32_16x16x32_f16(wA[0], b0v, aA, 0, 0, 0);
        aA = __builtin_amdgcn_mfma_f32_16x16x32_f16(wA[1], b1v, aA, 0, 0, 0);
        epi_write(aA, &h0f[wp][0]);
    };

    // L1 interval: c-reads issued first; single 4-deep chained accumulator -
    // bp MFMAs (register-ready) issue immediately and hide the c-read; then
    // c0,c1 chain in. No epilogue adds. Late h0 prefetch after epi_write
    // (R8's port-burst win).
    auto stepL1 = [&](int rc, int rbn, int wp, half8* bp) {
        half8 c0 = *(const half8*)&h1f[rc][rbase];
        half8 c1 = *(const half8*)&h1f[rc][rbase + 512];
        floatx4 aA = {bv1.x, bv1.y, bv1.z, bv1.w};
        aA = __builtin_amdgcn_mfma_f32_16x16x32_f16(wA[0], bp[0], aA, 0, 0, 0);
        aA = __builtin_amdgcn_mfma_f32_16x16x32_f16(wA[1], bp[1], aA, 0, 0, 0);
        aA = __builtin_amdgcn_mfma_f32_16x16x32_f16(wB[0], c0, aA, 0, 0, 0);
        aA = __builtin_amdgcn_mfma_f32_16x16x32_f16(wB[1], c1, aA, 0, 0, 0);
        epi_write(aA, &h1f[wp][0]);
        // late prefetch: LDS port idle here; h0f[rbn] stable this interval;
        // completion before next-interval overwrite = validated FIFO property.
        bp[0] = *(const half8*)&h0f[rbn][rbase];
        bp[1] = *(const half8*)&h0f[rbn][rbase + 512];
    };

    // ---- interval 0: L0 writes h0(0) -> parity 0 ----
    float xv = 0.f, xnext = 0.f;
    if (isL0) {
        const float xv0 = xp[0];
        float h[4];
#pragma unroll
        for (int r = 0; r < 4; ++r)
            h[r] = fast_tanh(__builtin_fmaf(xv0, f4e(wih0v, r), f4e(bv0, r)));
        uint2 u; u.x = pk16(h[0], h[1]); u.y = pk16(h[2], h[3]);
        *(uint2*)&h0f[0][wbase] = u;
        xv = xp[1];
        xnext = xp[2];
    }
    BAR();

    // ---- interval 1: L0 h0(1); L1 prefetches h0(0) ----
    half8 bp[2];
    if (isL0) {
        stepL0(0, 1, xv);
        xv = xnext; xnext = xp[3];
    } else {
        bp[0] = *(const half8*)&h0f[0][rbase];
        bp[1] = *(const half8*)&h0f[0][rbase + 512];
    }
    BAR();

    // ---- main loop: intervals i = 2..511 (pairs) ----
    // interval i: L0 computes h0(i); L1 computes h1(i-2), prefetches h0(i-1)
    for (int i = 2; i < 511; i += 2) {
        // P = 0
        if (isL0) {
            stepL0(1, 0, xv);
            xv = xnext; xnext = xp[(i + 2) & (TT - 1)];
        } else {
            stepL1(1, 1, 0, bp);
        }
        BAR();
        // P = 1
        if (isL0) {
            stepL0(0, 1, xv);
            xv = xnext; xnext = xp[(i + 3) & (TT - 1)];
        } else {
            stepL1(0, 0, 1, bp);
        }
        BAR();
    }

    // ---- tail interval 512: L1 computes h1(510), prefetches h0(511) ----
    if (!isL0) stepL1(1, 1, 0, bp);
    BAR();

    // ---- tail interval 513: L1 computes h1(511) in regs + FC dot ----
    float p = 0.f;
    if (!isL0) {
        half8 c0 = *(const half8*)&h1f[0][rbase];        // h1(510), parity 0
        half8 c1 = *(const half8*)&h1f[0][rbase + 512];
        floatx4 aA = {bv1.x, bv1.y, bv1.z, bv1.w};
        aA = __builtin_amdgcn_mfma_f32_16x16x32_f16(wA[0], bp[0], aA, 0, 0, 0);  // h0(511)
        aA = __builtin_amdgcn_mfma_f32_16x16x32_f16(wA[1], bp[1], aA, 0, 0, 0);
        aA = __builtin_amdgcn_mfma_f32_16x16x32_f16(wB[0], c0, aA, 0, 0, 0);
        aA = __builtin_amdgcn_mfma_f32_16x16x32_f16(wB[1], c1, aA, 0, 0, 0);
#pragma unroll
        for (int r = 0; r < 4; ++r) {
            const float h = fast_tanh(aA[r]);
            p = __builtin_fmaf(h, f4e(wfcv, r), p);
        }
        p += __shfl_xor(p, 16, 64);
        p += __shfl_xor(p, 32, 64);
        if (lane < 16) red[wq][lane] = p;
    }
    __syncthreads();
    if (w == 4 && lane < 16)
        out[b0 + lane] = red[0][lane] + red[1][lane] + red[2][lane] + red[3][lane] + b_fc[0];
}

extern "C" void kernel_launch(void* const* d_in, const int* in_sizes, int n_in,
                              void* d_out, int out_size, void* d_ws, size_t ws_size,
                              hipStream_t stream) {
    const float* x     = (const float*)d_in[0];
    const float* W_ih0 = (const float*)d_in[1];
    const float* W_hh0 = (const float*)d_in[2];
    const float* b_ih0 = (const float*)d_in[3];
    const float* b_hh0 = (const float*)d_in[4];
    const float* W_ih1 = (const float*)d_in[5];
    const float* W_hh1 = (const float*)d_in[6];
    const float* b_ih1 = (const float*)d_in[7];
    const float* b_hh1 = (const float*)d_in[8];
    const float* W_fc  = (const float*)d_in[9];
    const float* b_fc  = (const float*)d_in[10];
    float* out = (float*)d_out;

    rnn2_chain<<<128, 512, 0, stream>>>(x, W_ih0, W_hh0, b_ih0, b_hh0,
                                        W_ih1, W_hh1, b_ih1, b_hh1,
                                        W_fc, b_fc, out);
}